// Round 1
// baseline (18952.725 us; speedup 1.0000x reference)
//
#include <hip/hip_runtime.h>
#include <math.h>

// ---------------- model constants ----------------
#define BATCH 4
#define DIMM 1024
#define TTOK 1024
#define HEADS 16
#define HD 64
#define NLAYERS 6
#define CONVC 512
#define FFD 2816

__device__ __forceinline__ float silu_f(float x) { return x / (1.0f + __expf(-x)); }

// ---------------- temb ----------------
__global__ void temb1_kernel(const float* __restrict__ t, const float* __restrict__ w,
                             const float* __restrict__ b, float* __restrict__ out) {
    int idx = blockIdx.x * 256 + threadIdx.x;  // 4096
    int bb = idx >> 10, n = idx & 1023;
    out[idx] = silu_f(t[bb] * w[n] + b[n]);
}

__global__ __launch_bounds__(256) void temb2_kernel(const float* __restrict__ A, const float* __restrict__ W,
                                                    const float* __restrict__ b2, const float* __restrict__ yemb,
                                                    const int* __restrict__ y, float* __restrict__ out) {
    int wid = blockIdx.x * 4 + (threadIdx.x >> 6);  // 4096 outputs
    int lane = threadIdx.x & 63;
    int bb = wid >> 10, n = wid & 1023;
    const float* a = A + (bb << 10);
    const float* w = W + (n << 10);
    float s = 0.f;
    for (int k = lane << 2; k < 1024; k += 256) {
        float4 av = *(const float4*)&a[k];
        float4 wv = *(const float4*)&w[k];
        s += av.x * wv.x + av.y * wv.y + av.z * wv.z + av.w * wv.w;
    }
#pragma unroll
    for (int off = 32; off > 0; off >>= 1) s += __shfl_xor(s, off);
    if (lane == 0) {
        float vv = s + b2[n] + yemb[(size_t)y[bb] * 1024 + n];
        out[wid] = silu_f(vv);
    }
}

// ---------------- conv1: 4 -> 512, 5x5 SAME ----------------
__global__ __launch_bounds__(256) void conv1_kernel(const float* __restrict__ x, const float* __restrict__ w,
                                                    const float* __restrict__ bias, float* __restrict__ out) {
    int idx = blockIdx.x * 256 + threadIdx.x;  // 4*512*64*64 = 8388608
    int px = idx & 63;
    int py = (idx >> 6) & 63;
    int oc = (idx >> 12) & 511;
    int b = idx >> 21;
    float acc = bias[oc];
    for (int ic = 0; ic < 4; ic++) {
        const float* xp = x + (((b << 2) + ic) << 12);
        const float* wp = w + (oc * 4 + ic) * 25;
#pragma unroll
        for (int ky = 0; ky < 5; ky++) {
            int iy = py + ky - 2;
            if (iy < 0 || iy > 63) continue;
#pragma unroll
            for (int kx = 0; kx < 5; kx++) {
                int ix = px + kx - 2;
                if (ix < 0 || ix > 63) continue;
                acc += xp[(iy << 6) + ix] * wp[ky * 5 + kx];
            }
        }
    }
    out[idx] = acc;
}

// ---------------- fused silu + groupnorm (32 groups of 16 ch) ----------------
__global__ __launch_bounds__(256) void silu_gn_kernel(const float* __restrict__ in, float* __restrict__ out,
                                                      const float* __restrict__ g, const float* __restrict__ bt) {
    int blk = blockIdx.x;  // B*32 = 128
    int b = blk >> 5, grp = blk & 31, c0 = grp << 4;
    const float* p = in + (size_t)((b * 512 + c0)) * 4096;
    float* q = out + (size_t)((b * 512 + c0)) * 4096;
    int t = threadIdx.x;
    float s = 0.f, sq = 0.f;
    for (int i = t; i < 16384; i += 256) {  // 16384 float4 = 65536 elems
        float4 v = ((const float4*)p)[i];
        float a0 = silu_f(v.x), a1 = silu_f(v.y), a2 = silu_f(v.z), a3 = silu_f(v.w);
        s += a0 + a1 + a2 + a3;
        sq += a0 * a0 + a1 * a1 + a2 * a2 + a3 * a3;
    }
    __shared__ float2 red[256];
    red[t] = make_float2(s, sq);
    __syncthreads();
    for (int st = 128; st > 0; st >>= 1) {
        if (t < st) { red[t].x += red[t + st].x; red[t].y += red[t + st].y; }
        __syncthreads();
    }
    float mean = red[0].x * (1.f / 65536.f);
    float var = red[0].y * (1.f / 65536.f) - mean * mean;
    float rstd = rsqrtf(var + 1e-5f);
    for (int i = t; i < 16384; i += 256) {
        float4 v = ((const float4*)p)[i];
        int ch = c0 + (i >> 10);
        float gg = g[ch], bb = bt[ch];
        float4 o;
        o.x = (silu_f(v.x) - mean) * rstd * gg + bb;
        o.y = (silu_f(v.y) - mean) * rstd * gg + bb;
        o.z = (silu_f(v.z) - mean) * rstd * gg + bb;
        o.w = (silu_f(v.w) - mean) * rstd * gg + bb;
        ((float4*)q)[i] = o;
    }
}

// ---------------- conv2: 512 -> 512, 5x5 SAME, LDS tiled ----------------
__global__ __launch_bounds__(256) void conv2_kernel(const float* __restrict__ in, const float* __restrict__ w,
                                                    const float* __restrict__ bias, float* __restrict__ out) {
    // grid: (4 tiles, 128 oc-groups, 4 batch)
    int b = blockIdx.z;
    int oc0 = blockIdx.y << 2;
    int ty0 = (blockIdx.x >> 1) << 5;
    int tx0 = (blockIdx.x & 1) << 5;
    int t = threadIdx.x;
    __shared__ float tile[36][36];
    float acc[4][4];
#pragma unroll
    for (int p = 0; p < 4; p++)
#pragma unroll
        for (int j = 0; j < 4; j++) acc[p][j] = 0.f;
    int px = t & 31, r0 = t >> 5;
    for (int ic = 0; ic < 512; ic++) {
        const float* ip = in + (size_t)((b * 512 + ic)) * 4096;
        for (int i = t; i < 1296; i += 256) {
            int r = i / 36, c = i - r * 36;
            int gy = ty0 + r - 2, gx = tx0 + c - 2;
            tile[r][c] = (gy >= 0 && gy < 64 && gx >= 0 && gx < 64) ? ip[(gy << 6) + gx] : 0.f;
        }
        __syncthreads();
        const float* wp = w + ic * 25;
#pragma unroll
        for (int ky = 0; ky < 5; ky++) {
#pragma unroll
            for (int kx = 0; kx < 5; kx++) {
                float w0 = wp[(oc0 + 0) * 12800 + ky * 5 + kx];
                float w1v = wp[(oc0 + 1) * 12800 + ky * 5 + kx];
                float w2v = wp[(oc0 + 2) * 12800 + ky * 5 + kx];
                float w3v = wp[(oc0 + 3) * 12800 + ky * 5 + kx];
#pragma unroll
                for (int p = 0; p < 4; p++) {
                    float iv = tile[r0 + 8 * p + ky][px + kx];
                    acc[p][0] += iv * w0;
                    acc[p][1] += iv * w1v;
                    acc[p][2] += iv * w2v;
                    acc[p][3] += iv * w3v;
                }
            }
        }
        __syncthreads();
    }
#pragma unroll
    for (int p = 0; p < 4; p++) {
        int gy = ty0 + r0 + 8 * p, gx = tx0 + px;
#pragma unroll
        for (int j = 0; j < 4; j++)
            out[(size_t)((b * 512 + oc0 + j)) * 4096 + (gy << 6) + gx] = acc[p][j] + bias[oc0 + j];
    }
}

// ---------------- patchify (B,512,64,64) -> (B,1024,2048) ----------------
__global__ void patchify_kernel(const float* __restrict__ hn, float* __restrict__ pout) {
    int idx = blockIdx.x * 256 + threadIdx.x;  // 8388608
    int kf = idx & 2047;
    int tk = (idx >> 11) & 1023;
    int b = idx >> 21;
    int c = kf >> 2;
    int a = (kf >> 1) & 1;
    int b2 = kf & 1;
    int ph = tk >> 5, pw = tk & 31;
    pout[idx] = hn[(size_t)((b * 512 + c)) * 4096 + (((ph << 1) + a) << 6) + (pw << 1) + b2];
}

// ---------------- generic fp32 GEMM: C = A(MxK) @ W(NxK)^T (+bias) (opt gated residual add) ----
__global__ __launch_bounds__(256) void gemm64_kernel(const float* __restrict__ A, const float* __restrict__ W,
                                                     const float* __restrict__ bias, float* __restrict__ C,
                                                     int M, int N, int K,
                                                     const float* __restrict__ gate, int gateStride) {
    __shared__ float As[16][68];
    __shared__ float Ws[16][68];
    int t = threadIdx.x;
    int tx = t & 15, ty = t >> 4;
    int m0 = blockIdx.y << 6, n0 = blockIdx.x << 6;
    int lr = t >> 2, lk = (t & 3) << 2;
    const float* Ap = A + (size_t)(m0 + lr) * K + lk;
    const float* Wp = W + (size_t)(n0 + lr) * K + lk;
    float acc[4][4];
#pragma unroll
    for (int i = 0; i < 4; i++)
#pragma unroll
        for (int j = 0; j < 4; j++) acc[i][j] = 0.f;
    for (int k0 = 0; k0 < K; k0 += 16) {
        float4 av = *(const float4*)(Ap + k0);
        float4 wv = *(const float4*)(Wp + k0);
        As[lk + 0][lr] = av.x; As[lk + 1][lr] = av.y; As[lk + 2][lr] = av.z; As[lk + 3][lr] = av.w;
        Ws[lk + 0][lr] = wv.x; Ws[lk + 1][lr] = wv.y; Ws[lk + 2][lr] = wv.z; Ws[lk + 3][lr] = wv.w;
        __syncthreads();
#pragma unroll
        for (int kk = 0; kk < 16; kk++) {
            float4 a4 = *(const float4*)&As[kk][ty << 2];
            float4 b4 = *(const float4*)&Ws[kk][tx << 2];
            acc[0][0] += a4.x * b4.x; acc[0][1] += a4.x * b4.y; acc[0][2] += a4.x * b4.z; acc[0][3] += a4.x * b4.w;
            acc[1][0] += a4.y * b4.x; acc[1][1] += a4.y * b4.y; acc[1][2] += a4.y * b4.z; acc[1][3] += a4.y * b4.w;
            acc[2][0] += a4.z * b4.x; acc[2][1] += a4.z * b4.y; acc[2][2] += a4.z * b4.z; acc[2][3] += a4.z * b4.w;
            acc[3][0] += a4.w * b4.x; acc[3][1] += a4.w * b4.y; acc[3][2] += a4.w * b4.z; acc[3][3] += a4.w * b4.w;
        }
        __syncthreads();
    }
#pragma unroll
    for (int i = 0; i < 4; i++) {
        int m = m0 + (ty << 2) + i;
#pragma unroll
        for (int j = 0; j < 4; j++) {
            int n = n0 + (tx << 2) + j;
            float v = acc[i][j];
            if (bias) v += bias[n];
            size_t off = (size_t)m * N + n;
            if (gate)
                C[off] += gate[(m >> 10) * gateStride + n] * v;
            else
                C[off] = v;
        }
    }
}

// ---------------- layernorm + modulate ----------------
__global__ __launch_bounds__(256) void ln_mod_kernel(const float* __restrict__ in, float* __restrict__ out,
                                                     const float* __restrict__ g, const float* __restrict__ bt,
                                                     const float* __restrict__ shiftb, const float* __restrict__ scaleb,
                                                     int modStride, float eps) {
    int row = blockIdx.x;  // 4096
    int b = row >> 10;
    int t = threadIdx.x;
    const float* p = in + ((size_t)row << 10);
    float4 x = ((const float4*)p)[t];
    float s = x.x + x.y + x.z + x.w;
    float sq = x.x * x.x + x.y * x.y + x.z * x.z + x.w * x.w;
    __shared__ float2 red[256];
    red[t] = make_float2(s, sq);
    __syncthreads();
    for (int st = 128; st > 0; st >>= 1) {
        if (t < st) { red[t].x += red[t + st].x; red[t].y += red[t + st].y; }
        __syncthreads();
    }
    float mean = red[0].x * (1.f / 1024.f);
    float var = red[0].y * (1.f / 1024.f) - mean * mean;
    float rstd = rsqrtf(var + eps);
    const float* sh = shiftb + b * modStride;
    const float* sc = scaleb + b * modStride;
    int c = t << 2;
    float4 o;
    {
        float xn = (x.x - mean) * rstd; if (g) xn = xn * g[c + 0] + bt[c + 0];
        o.x = xn * (1.f + sc[c + 0]) + sh[c + 0];
    }
    {
        float xn = (x.y - mean) * rstd; if (g) xn = xn * g[c + 1] + bt[c + 1];
        o.y = xn * (1.f + sc[c + 1]) + sh[c + 1];
    }
    {
        float xn = (x.z - mean) * rstd; if (g) xn = xn * g[c + 2] + bt[c + 2];
        o.z = xn * (1.f + sc[c + 2]) + sh[c + 2];
    }
    {
        float xn = (x.w - mean) * rstd; if (g) xn = xn * g[c + 3] + bt[c + 3];
        o.w = xn * (1.f + sc[c + 3]) + sh[c + 3];
    }
    ((float4*)(out + ((size_t)row << 10)))[t] = o;
}

// ---------------- rope (in-place on (B,T,H,D)) ----------------
__global__ void rope_kernel(float* __restrict__ p) {
    int idx = blockIdx.x * 256 + threadIdx.x;  // 2097152
    int j = idx & 31;
    int h = (idx >> 5) & 15;
    int tt = (idx >> 9) & 1023;
    int b = idx >> 19;
    float inv = powf(10000.f, -(float)j * (1.f / 32.f));
    float ang = (float)tt * inv;
    float cs = cosf(ang), sn = sinf(ang);
    size_t base = (size_t)(((b << 10) + tt)) * 1024 + (h << 6) + (j << 1);
    float2 v = *(float2*)&p[base];
    float2 o;
    o.x = v.x * cs - v.y * sn;
    o.y = v.x * sn + v.y * cs;
    *(float2*)&p[base] = o;
}

// ---------------- K transpose: (B,T,H,D) -> (B,H,D,T) ----------------
__global__ void ktrans_kernel(const float* __restrict__ k, float* __restrict__ kT) {
    int idx = blockIdx.x * 256 + threadIdx.x;  // 4194304
    int s = idx & 1023;
    int d = (idx >> 10) & 63;
    int h = (idx >> 16) & 15;
    int b = idx >> 20;
    kT[idx] = k[(size_t)(((b << 10) + s)) * 1024 + (h << 6) + d];
}

// ---------------- fused attention: 8 query rows per block ----------------
__global__ __launch_bounds__(256) void attn_kernel(const float* __restrict__ q, const float* __restrict__ kT,
                                                   const float* __restrict__ v, float* __restrict__ o) {
    // grid: (T/8=128, H=16, B=4)
    int b = blockIdx.z, h = blockIdx.y, tq0 = blockIdx.x << 3;
    int t = threadIdx.x;
    __shared__ float qv[8][64];
    __shared__ float sc[8][1024];
    __shared__ float po[4][8][64];
    __shared__ float red[256];
    __shared__ float rowsum[8];
    for (int i = t; i < 512; i += 256) {
        int r = i >> 6, d = i & 63;
        qv[r][d] = q[(size_t)(((b << 10) + tq0 + r)) * 1024 + (h << 6) + d];
    }
    __syncthreads();
    float4 acc4[8];
#pragma unroll
    for (int r = 0; r < 8; r++) acc4[r] = make_float4(0.f, 0.f, 0.f, 0.f);
    const float* kTp = kT + (size_t)(((b << 4) + h) << 6) * 1024;
    for (int d = 0; d < 64; d++) {
        float4 kv = *(const float4*)&kTp[(d << 10) + (t << 2)];
#pragma unroll
        for (int r = 0; r < 8; r++) {
            float qd = qv[r][d];
            acc4[r].x += kv.x * qd; acc4[r].y += kv.y * qd;
            acc4[r].z += kv.z * qd; acc4[r].w += kv.w * qd;
        }
    }
#pragma unroll
    for (int r = 0; r < 8; r++) {
        sc[r][(t << 2) + 0] = acc4[r].x * 0.125f;
        sc[r][(t << 2) + 1] = acc4[r].y * 0.125f;
        sc[r][(t << 2) + 2] = acc4[r].z * 0.125f;
        sc[r][(t << 2) + 3] = acc4[r].w * 0.125f;
    }
    __syncthreads();
    for (int r = 0; r < 8; r++) {
        float m = fmaxf(fmaxf(sc[r][(t << 2)], sc[r][(t << 2) + 1]),
                        fmaxf(sc[r][(t << 2) + 2], sc[r][(t << 2) + 3]));
        red[t] = m;
        __syncthreads();
        for (int st = 128; st > 0; st >>= 1) {
            if (t < st) red[t] = fmaxf(red[t], red[t + st]);
            __syncthreads();
        }
        float rmax = red[0];
        __syncthreads();
        float ssum = 0.f;
#pragma unroll
        for (int u = 0; u < 4; u++) {
            float e = __expf(sc[r][(t << 2) + u] - rmax);
            sc[r][(t << 2) + u] = e;
            ssum += e;
        }
        red[t] = ssum;
        __syncthreads();
        for (int st = 128; st > 0; st >>= 1) {
            if (t < st) red[t] += red[t + st];
            __syncthreads();
        }
        if (t == 0) rowsum[r] = red[0];
        __syncthreads();
    }
    int d = t & 63, c = t >> 6;
    float pacc[8];
#pragma unroll
    for (int r = 0; r < 8; r++) pacc[r] = 0.f;
    for (int i = 0; i < 256; i++) {
        int s = (c << 8) + i;
        float vv = v[(size_t)(((b << 10) + s)) * 1024 + (h << 6) + d];
#pragma unroll
        for (int r = 0; r < 8; r++) pacc[r] += sc[r][s] * vv;
    }
#pragma unroll
    for (int r = 0; r < 8; r++) po[c][r][d] = pacc[r];
    __syncthreads();
    for (int i = t; i < 512; i += 256) {
        int r = i >> 6, dd = i & 63;
        float oo = (po[0][r][dd] + po[1][r][dd] + po[2][r][dd] + po[3][r][dd]) / rowsum[r];
        o[(size_t)(((b << 10) + tq0 + r)) * 1024 + (h << 6) + dd] = oo;
    }
}

// ---------------- small row-vector GEMM: out(M x N) = A(M x K) @ W(N x K)^T + bias ----
__global__ __launch_bounds__(256) void rowvec_gemm_kernel(const float* __restrict__ A, const float* __restrict__ W,
                                                          const float* __restrict__ bias, float* __restrict__ out,
                                                          int N, int K) {
    int wid = blockIdx.x * 4 + (threadIdx.x >> 6);
    int lane = threadIdx.x & 63;
    int b = wid / N, n = wid - b * N;
    const float* a = A + (size_t)b * K;
    const float* w = W + (size_t)n * K;
    float s = 0.f;
    for (int k = lane << 2; k < K; k += 256) {
        float4 av = *(const float4*)&a[k];
        float4 wv = *(const float4*)&w[k];
        s += av.x * wv.x + av.y * wv.y + av.z * wv.z + av.w * wv.w;
    }
#pragma unroll
    for (int off = 32; off > 0; off >>= 1) s += __shfl_xor(s, off);
    if (lane == 0) out[wid] = s + (bias ? bias[n] : 0.f);
}

// ---------------- swiglu elementwise: f1 = silu(f1)*f3 ----------------
__global__ void swiglu_kernel(float* __restrict__ f1, const float* __restrict__ f3, int n) {
    int idx = blockIdx.x * 256 + threadIdx.x;
    if (idx < n) {
        float a = f1[idx];
        f1[idx] = (a / (1.f + __expf(-a))) * f3[idx];
    }
}

// ---------------- final projection: (4096x1024) @ (16x1024)^T + bias ----------------
__global__ __launch_bounds__(256) void fin_gemm_kernel(const float* __restrict__ zf, const float* __restrict__ w,
                                                       const float* __restrict__ bias, float* __restrict__ out) {
    int idx = blockIdx.x * 256 + threadIdx.x;  // 65536
    int m = idx >> 4, n = idx & 15;
    const float* a = zf + ((size_t)m << 10);
    const float* wp = w + ((size_t)n << 10);
    float s = 0.f;
    for (int k = 0; k < 1024; k += 4) {
        float4 av = *(const float4*)&a[k];
        float4 wv = *(const float4*)&wp[k];
        s += av.x * wv.x + av.y * wv.y + av.z * wv.z + av.w * wv.w;
    }
    out[idx] = s + bias[n];
}

// ---------------- unpatchify -> (B,4,64,64) ----------------
__global__ void unpatch_kernel(const float* __restrict__ ot, float* __restrict__ out) {
    int idx = blockIdx.x * 256 + threadIdx.x;  // 65536
    int x = idx & 63;
    int yy = (idx >> 6) & 63;
    int ci = (idx >> 12) & 3;
    int b = idx >> 14;
    out[idx] = ot[(size_t)(((b << 10) + ((yy >> 1) << 5) + (x >> 1))) * 16 + (((yy & 1) << 1) + (x & 1)) * 4 + ci];
}

// ---------------- host orchestration ----------------
extern "C" void kernel_launch(void* const* d_in, const int* in_sizes, int n_in,
                              void* d_out, int out_size, void* d_ws, size_t ws_size,
                              hipStream_t stream) {
    const float* x       = (const float*)d_in[0];
    const float* tin     = (const float*)d_in[1];
    const int*   y       = (const int*)d_in[2];
    const float* conv1_w = (const float*)d_in[3];
    const float* conv1_b = (const float*)d_in[4];
    const float* gn1_g   = (const float*)d_in[5];
    const float* gn1_b   = (const float*)d_in[6];
    const float* conv2_w = (const float*)d_in[7];
    const float* conv2_b = (const float*)d_in[8];
    const float* gn2_g   = (const float*)d_in[9];
    const float* gn2_b   = (const float*)d_in[10];
    const float* xemb_w  = (const float*)d_in[11];
    const float* xemb_b  = (const float*)d_in[12];
    const float* t1_w    = (const float*)d_in[13];
    const float* t1_b    = (const float*)d_in[14];
    const float* t2_w    = (const float*)d_in[15];
    const float* t2_b    = (const float*)d_in[16];
    const float* y_emb   = (const float*)d_in[17];
    const float* wq      = (const float*)d_in[18];
    const float* wk      = (const float*)d_in[19];
    const float* wv      = (const float*)d_in[20];
    const float* wo      = (const float*)d_in[21];
    const float* w1      = (const float*)d_in[22];
    const float* w3      = (const float*)d_in[23];   // note: dict order is w1, w3, w2
    const float* w2      = (const float*)d_in[24];
    const float* ada_w   = (const float*)d_in[25];
    const float* ada_b   = (const float*)d_in[26];
    const float* an_g    = (const float*)d_in[27];
    const float* an_b    = (const float*)d_in[28];
    const float* fn_g    = (const float*)d_in[29];
    const float* fn_b    = (const float*)d_in[30];
    const float* fin_ada_w = (const float*)d_in[31];
    const float* fin_ada_b = (const float*)d_in[32];
    const float* fin_w   = (const float*)d_in[33];
    const float* fin_b   = (const float*)d_in[34];

    float* ws = (float*)d_ws;
    // workspace layout (float elements), total ~31.04M floats = ~124 MB
    float* A0  = ws;                 // 8388608  : conv h / patches / q(0..4M), k(4M..8M)
    float* A1  = ws + 8388608;       // 8388608  : conv hn / v(0..4M), attnout(4M..8M)
    float* Z   = ws + 16777216;      // 4194304  : residual stream
    float* HH  = ws + 20971520;      // 4194304  : ln output / kT / zf
    float* F1  = ws + 25165824;      // 2883584  : ff chunk buf 1
    float* F3  = ws + 28049408;      // 2883584  : ff chunk buf 2
    float* TMB = ws + 30932992;      // 4096
    float* CSI = TMB + 4096;         // 4096     : c_silu
    float* MODS = CSI + 4096;        // 24576
    float* FM  = MODS + 24576;       // 8192
    float* OT  = FM + 8192;          // 65536    : pre-unpatchify output

    // conditioning
    temb1_kernel<<<16, 256, 0, stream>>>(tin, t1_w, t1_b, TMB);
    temb2_kernel<<<1024, 256, 0, stream>>>(TMB, t2_w, t2_b, y_emb, y, CSI);

    // conv stem
    conv1_kernel<<<32768, 256, 0, stream>>>(x, conv1_w, conv1_b, A0);
    silu_gn_kernel<<<128, 256, 0, stream>>>(A0, A1, gn1_g, gn1_b);
    conv2_kernel<<<dim3(4, 128, 4), 256, 0, stream>>>(A1, conv2_w, conv2_b, A0);
    silu_gn_kernel<<<128, 256, 0, stream>>>(A0, A1, gn2_g, gn2_b);
    patchify_kernel<<<32768, 256, 0, stream>>>(A1, A0);
    gemm64_kernel<<<dim3(16, 64), 256, 0, stream>>>(A0, xemb_w, xemb_b, Z, 4096, 1024, 2048, nullptr, 0);

    for (int i = 0; i < NLAYERS; i++) {
        const float* wq_i = wq + (size_t)i * 1048576;
        const float* wk_i = wk + (size_t)i * 1048576;
        const float* wv_i = wv + (size_t)i * 1048576;
        const float* wo_i = wo + (size_t)i * 1048576;
        const float* w1_i = w1 + (size_t)i * 2883584;
        const float* w3_i = w3 + (size_t)i * 2883584;
        const float* w2_i = w2 + (size_t)i * 2883584;
        const float* ada_w_i = ada_w + (size_t)i * 6291456;
        const float* ada_b_i = ada_b + (size_t)i * 6144;
        const float* an_g_i = an_g + (size_t)i * 1024;
        const float* an_b_i = an_b + (size_t)i * 1024;
        const float* fn_g_i = fn_g + (size_t)i * 1024;
        const float* fn_b_i = fn_b + (size_t)i * 1024;

        // adaLN mods: (4 x 6144)
        rowvec_gemm_kernel<<<6144, 256, 0, stream>>>(CSI, ada_w_i, ada_b_i, MODS, 6144, 1024);
        // attn branch
        ln_mod_kernel<<<4096, 256, 0, stream>>>(Z, HH, an_g_i, an_b_i, MODS + 0, MODS + 1024, 6144, 1e-5f);
        gemm64_kernel<<<dim3(16, 64), 256, 0, stream>>>(HH, wq_i, nullptr, A0, 4096, 1024, 1024, nullptr, 0);
        gemm64_kernel<<<dim3(16, 64), 256, 0, stream>>>(HH, wk_i, nullptr, A0 + 4194304, 4096, 1024, 1024, nullptr, 0);
        gemm64_kernel<<<dim3(16, 64), 256, 0, stream>>>(HH, wv_i, nullptr, A1, 4096, 1024, 1024, nullptr, 0);
        rope_kernel<<<8192, 256, 0, stream>>>(A0);
        rope_kernel<<<8192, 256, 0, stream>>>(A0 + 4194304);
        ktrans_kernel<<<16384, 256, 0, stream>>>(A0 + 4194304, HH);  // HH now = kT
        attn_kernel<<<dim3(128, 16, 4), 256, 0, stream>>>(A0, HH, A1, A1 + 4194304);
        gemm64_kernel<<<dim3(16, 64), 256, 0, stream>>>(A1 + 4194304, wo_i, nullptr, Z, 4096, 1024, 1024,
                                                        MODS + 2048, 6144);
        // ff branch
        ln_mod_kernel<<<4096, 256, 0, stream>>>(Z, HH, fn_g_i, fn_b_i, MODS + 3072, MODS + 4096, 6144, 1e-5f);
        for (int cc = 0; cc < 4; cc++) {
            const float* hc = HH + (size_t)cc * 1048576;
            gemm64_kernel<<<dim3(44, 16), 256, 0, stream>>>(hc, w1_i, nullptr, F1, 1024, 2816, 1024, nullptr, 0);
            gemm64_kernel<<<dim3(44, 16), 256, 0, stream>>>(hc, w3_i, nullptr, F3, 1024, 2816, 1024, nullptr, 0);
            swiglu_kernel<<<11264, 256, 0, stream>>>(F1, F3, 2883584);
            gemm64_kernel<<<dim3(16, 16), 256, 0, stream>>>(F1, w2_i, nullptr, Z + (size_t)cc * 1048576,
                                                            1024, 1024, 2816, MODS + cc * 6144 + 5120, 0);
        }
    }

    // final head
    rowvec_gemm_kernel<<<2048, 256, 0, stream>>>(CSI, fin_ada_w, fin_ada_b, FM, 2048, 1024);
    ln_mod_kernel<<<4096, 256, 0, stream>>>(Z, HH, nullptr, nullptr, FM + 0, FM + 1024, 2048, 1e-6f);
    fin_gemm_kernel<<<256, 256, 0, stream>>>(HH, fin_w, fin_b, OT);
    unpatch_kernel<<<256, 256, 0, stream>>>(OT, (float*)d_out);
}

// Round 2
// 9887.369 us; speedup vs baseline: 1.9169x; 1.9169x over previous
//
#include <hip/hip_runtime.h>
#include <math.h>

#define NLAYERS 6

typedef unsigned short u16;
typedef unsigned int u32;
typedef __attribute__((ext_vector_type(4))) float floatx4;
typedef __attribute__((ext_vector_type(8))) short bf16x8;

__device__ __forceinline__ float silu_f(float x) { return x / (1.0f + __expf(-x)); }

__device__ __forceinline__ u16 f2b(float f) {
    union { float f; u32 u; } x; x.f = f;
    u32 r = x.u + 0x7fffu + ((x.u >> 16) & 1u);
    return (u16)(r >> 16);
}
__device__ __forceinline__ float b2f(u16 u) {
    union { u32 u; float f; } x; x.u = ((u32)u) << 16;
    return x.f;
}

__device__ __forceinline__ void gload_lds16(const void* g, void* l) {
    __builtin_amdgcn_global_load_lds((const __attribute__((address_space(1))) u32*)g,
                                     (__attribute__((address_space(3))) u32*)l, 16, 0, 0);
}

// stage a 128-row x 32-col bf16 tile (row-major [128][32]) from global (row stride ldk) into LDS
__device__ __forceinline__ void stage128x32(const u16* __restrict__ src, int ldk, short* lds, int t) {
    int w = t >> 6;
#pragma unroll
    for (int rep = 0; rep < 2; rep++) {
        int s = rep * 256 + t;
        int row = s >> 2, kp = s & 3;
        const u16* g = src + (size_t)row * ldk + kp * 8;
        short* lb = lds + (size_t)(rep * 256 + w * 64) * 8;  // wave-uniform base
        gload_lds16((const void*)g, (void*)lb);
    }
}

// ---------------- bf16 MFMA GEMM: C(MxN) = A(MxK) @ W(NxK)^T ----------------
// modes: accZ != null -> Z += gate * acc ; else outB != null -> bf16 store ; else outF = acc (+bias)
__global__ __launch_bounds__(256) void mfma_gemm_kernel(
    const u16* __restrict__ A, const u16* __restrict__ W, int M, int N, int K,
    float* __restrict__ outF, u16* __restrict__ outB, const float* __restrict__ bias,
    float* __restrict__ accZ, const float* __restrict__ gate, int gateStride) {
    __shared__ __align__(16) short As[128 * 32];
    __shared__ __align__(16) short Bs[128 * 32];
    int t = threadIdx.x;
    int lane = t & 63, wave = t >> 6;
    int wm = wave >> 1, wn = wave & 1;
    int m0 = blockIdx.y << 7, n0 = blockIdx.x << 7;
    int lm = lane & 15, kg = lane >> 4;
    floatx4 zero4 = {0.f, 0.f, 0.f, 0.f};
    floatx4 acc[4][4];
#pragma unroll
    for (int i = 0; i < 4; i++)
#pragma unroll
        for (int j = 0; j < 4; j++) acc[i][j] = zero4;
    const u16* Arow = A + (size_t)m0 * K;
    const u16* Wrow = W + (size_t)n0 * K;
    int aoff[4], boff[4];
#pragma unroll
    for (int i = 0; i < 4; i++) {
        aoff[i] = (wm * 64 + i * 16 + lm) * 32 + kg * 8;
        boff[i] = (wn * 64 + i * 16 + lm) * 32 + kg * 8;
    }
    for (int k0 = 0; k0 < K; k0 += 32) {
        stage128x32(Arow + k0, K, As, t);
        stage128x32(Wrow + k0, K, Bs, t);
        __syncthreads();
        bf16x8 af[4], bfr[4];
#pragma unroll
        for (int i = 0; i < 4; i++) af[i] = *(const bf16x8*)&As[aoff[i]];
#pragma unroll
        for (int j = 0; j < 4; j++) bfr[j] = *(const bf16x8*)&Bs[boff[j]];
#pragma unroll
        for (int i = 0; i < 4; i++)
#pragma unroll
            for (int j = 0; j < 4; j++)
                acc[i][j] = __builtin_amdgcn_mfma_f32_16x16x32_bf16(af[i], bfr[j], acc[i][j], 0, 0, 0);
        __syncthreads();
    }
#pragma unroll
    for (int i = 0; i < 4; i++) {
        int rbase = m0 + wm * 64 + i * 16 + kg * 4;
#pragma unroll
        for (int j = 0; j < 4; j++) {
            int c = n0 + wn * 64 + j * 16 + lm;
#pragma unroll
            for (int r = 0; r < 4; r++) {
                float v = acc[i][j][r];
                int row = rbase + r;
                size_t off = (size_t)row * N + c;
                if (accZ) {
                    accZ[off] += gate[(row >> 10) * gateStride + c] * v;
                } else if (outB) {
                    outB[off] = f2b(v);
                } else {
                    if (bias) v += bias[c];
                    outF[off] = v;
                }
            }
        }
    }
}

// ---------------- fused w1/w3 + swiglu: out = bf16( silu(A@W1^T) * (A@W3^T) ) ----------------
__global__ __launch_bounds__(256) void mfma_gemm_swiglu_kernel(
    const u16* __restrict__ A, const u16* __restrict__ W1, const u16* __restrict__ W3,
    int M, int N, int K, u16* __restrict__ outB) {
    __shared__ __align__(16) short As[128 * 32];
    __shared__ __align__(16) short B1s[128 * 32];
    __shared__ __align__(16) short B3s[128 * 32];
    int t = threadIdx.x;
    int lane = t & 63, wave = t >> 6;
    int wm = wave >> 1, wn = wave & 1;
    int m0 = blockIdx.y << 7, n0 = blockIdx.x << 7;
    int lm = lane & 15, kg = lane >> 4;
    floatx4 zero4 = {0.f, 0.f, 0.f, 0.f};
    floatx4 acc1[4][4], acc3[4][4];
#pragma unroll
    for (int i = 0; i < 4; i++)
#pragma unroll
        for (int j = 0; j < 4; j++) { acc1[i][j] = zero4; acc3[i][j] = zero4; }
    const u16* Arow = A + (size_t)m0 * K;
    const u16* W1row = W1 + (size_t)n0 * K;
    const u16* W3row = W3 + (size_t)n0 * K;
    int aoff[4], boff[4];
#pragma unroll
    for (int i = 0; i < 4; i++) {
        aoff[i] = (wm * 64 + i * 16 + lm) * 32 + kg * 8;
        boff[i] = (wn * 64 + i * 16 + lm) * 32 + kg * 8;
    }
    for (int k0 = 0; k0 < K; k0 += 32) {
        stage128x32(Arow + k0, K, As, t);
        stage128x32(W1row + k0, K, B1s, t);
        stage128x32(W3row + k0, K, B3s, t);
        __syncthreads();
        bf16x8 af[4], b1[4], b3[4];
#pragma unroll
        for (int i = 0; i < 4; i++) af[i] = *(const bf16x8*)&As[aoff[i]];
#pragma unroll
        for (int j = 0; j < 4; j++) { b1[j] = *(const bf16x8*)&B1s[boff[j]]; b3[j] = *(const bf16x8*)&B3s[boff[j]]; }
#pragma unroll
        for (int i = 0; i < 4; i++)
#pragma unroll
            for (int j = 0; j < 4; j++) {
                acc1[i][j] = __builtin_amdgcn_mfma_f32_16x16x32_bf16(af[i], b1[j], acc1[i][j], 0, 0, 0);
                acc3[i][j] = __builtin_amdgcn_mfma_f32_16x16x32_bf16(af[i], b3[j], acc3[i][j], 0, 0, 0);
            }
        __syncthreads();
    }
#pragma unroll
    for (int i = 0; i < 4; i++) {
        int rbase = m0 + wm * 64 + i * 16 + kg * 4;
#pragma unroll
        for (int j = 0; j < 4; j++) {
            int c = n0 + wn * 64 + j * 16 + lm;
#pragma unroll
            for (int r = 0; r < 4; r++) {
                int row = rbase + r;
                float v = silu_f(acc1[i][j][r]) * acc3[i][j][r];
                outB[(size_t)row * N + c] = f2b(v);
            }
        }
    }
}

// ---------------- fp32 -> bf16 conversion (up to 4 equal-size arrays) ----------------
__global__ void f2bN_kernel(const float* __restrict__ p0, const float* __restrict__ p1,
                            const float* __restrict__ p2, const float* __restrict__ p3,
                            u16* __restrict__ out, int n4each, int nptr) {
    int idx = blockIdx.x * 256 + threadIdx.x;
    if (idx >= n4each * nptr) return;
    int which = idx / n4each;
    int i = idx - which * n4each;
    const float* p = (which == 0) ? p0 : (which == 1) ? p1 : (which == 2) ? p2 : p3;
    float4 v = ((const float4*)p)[i];
    ushort4 o;
    o.x = f2b(v.x); o.y = f2b(v.y); o.z = f2b(v.z); o.w = f2b(v.w);
    ((ushort4*)out)[idx] = o;
}

// ---------------- temb ----------------
__global__ void temb1_kernel(const float* __restrict__ t, const float* __restrict__ w,
                             const float* __restrict__ b, float* __restrict__ out) {
    int idx = blockIdx.x * 256 + threadIdx.x;
    int bb = idx >> 10, n = idx & 1023;
    out[idx] = silu_f(t[bb] * w[n] + b[n]);
}

__global__ __launch_bounds__(256) void temb2_kernel(const float* __restrict__ A, const float* __restrict__ W,
                                                    const float* __restrict__ b2, const float* __restrict__ yemb,
                                                    const int* __restrict__ y, float* __restrict__ out) {
    int wid = blockIdx.x * 4 + (threadIdx.x >> 6);
    int lane = threadIdx.x & 63;
    int bb = wid >> 10, n = wid & 1023;
    const float* a = A + (bb << 10);
    const float* w = W + (n << 10);
    float s = 0.f;
    for (int k = lane << 2; k < 1024; k += 256) {
        float4 av = *(const float4*)&a[k];
        float4 wv = *(const float4*)&w[k];
        s += av.x * wv.x + av.y * wv.y + av.z * wv.z + av.w * wv.w;
    }
#pragma unroll
    for (int off = 32; off > 0; off >>= 1) s += __shfl_xor(s, off);
    if (lane == 0) {
        float vv = s + b2[n] + yemb[(size_t)y[bb] * 1024 + n];
        out[wid] = silu_f(vv);
    }
}

// ---------------- conv1: 4 -> 512, 5x5 SAME ----------------
__global__ __launch_bounds__(256) void conv1_kernel(const float* __restrict__ x, const float* __restrict__ w,
                                                    const float* __restrict__ bias, float* __restrict__ out) {
    int idx = blockIdx.x * 256 + threadIdx.x;
    int px = idx & 63;
    int py = (idx >> 6) & 63;
    int oc = (idx >> 12) & 511;
    int b = idx >> 21;
    float acc = bias[oc];
    for (int ic = 0; ic < 4; ic++) {
        const float* xp = x + (((b << 2) + ic) << 12);
        const float* wp = w + (oc * 4 + ic) * 25;
#pragma unroll
        for (int ky = 0; ky < 5; ky++) {
            int iy = py + ky - 2;
            if (iy < 0 || iy > 63) continue;
#pragma unroll
            for (int kx = 0; kx < 5; kx++) {
                int ix = px + kx - 2;
                if (ix < 0 || ix > 63) continue;
                acc += xp[(iy << 6) + ix] * wp[ky * 5 + kx];
            }
        }
    }
    out[idx] = acc;
}

// ---------------- fused silu + groupnorm ----------------
__global__ __launch_bounds__(256) void silu_gn_kernel(const float* __restrict__ in, float* __restrict__ out,
                                                      const float* __restrict__ g, const float* __restrict__ bt) {
    int blk = blockIdx.x;
    int b = blk >> 5, grp = blk & 31, c0 = grp << 4;
    const float* p = in + (size_t)((b * 512 + c0)) * 4096;
    float* q = out + (size_t)((b * 512 + c0)) * 4096;
    int t = threadIdx.x;
    float s = 0.f, sq = 0.f;
    for (int i = t; i < 16384; i += 256) {
        float4 v = ((const float4*)p)[i];
        float a0 = silu_f(v.x), a1 = silu_f(v.y), a2 = silu_f(v.z), a3 = silu_f(v.w);
        s += a0 + a1 + a2 + a3;
        sq += a0 * a0 + a1 * a1 + a2 * a2 + a3 * a3;
    }
    __shared__ float2 red[256];
    red[t] = make_float2(s, sq);
    __syncthreads();
    for (int st = 128; st > 0; st >>= 1) {
        if (t < st) { red[t].x += red[t + st].x; red[t].y += red[t + st].y; }
        __syncthreads();
    }
    float mean = red[0].x * (1.f / 65536.f);
    float var = red[0].y * (1.f / 65536.f) - mean * mean;
    float rstd = rsqrtf(var + 1e-5f);
    for (int i = t; i < 16384; i += 256) {
        float4 v = ((const float4*)p)[i];
        int ch = c0 + (i >> 10);
        float gg = g[ch], bb = bt[ch];
        float4 o;
        o.x = (silu_f(v.x) - mean) * rstd * gg + bb;
        o.y = (silu_f(v.y) - mean) * rstd * gg + bb;
        o.z = (silu_f(v.z) - mean) * rstd * gg + bb;
        o.w = (silu_f(v.w) - mean) * rstd * gg + bb;
        ((float4*)q)[i] = o;
    }
}

// ---------------- conv2: 512 -> 512, 5x5 SAME (fp32, LDS tiled) ----------------
__global__ __launch_bounds__(256) void conv2_kernel(const float* __restrict__ in, const float* __restrict__ w,
                                                    const float* __restrict__ bias, float* __restrict__ out) {
    int b = blockIdx.z;
    int oc0 = blockIdx.y << 2;
    int ty0 = (blockIdx.x >> 1) << 5;
    int tx0 = (blockIdx.x & 1) << 5;
    int t = threadIdx.x;
    __shared__ float tile[36][36];
    float acc[4][4];
#pragma unroll
    for (int p = 0; p < 4; p++)
#pragma unroll
        for (int j = 0; j < 4; j++) acc[p][j] = 0.f;
    int px = t & 31, r0 = t >> 5;
    for (int ic = 0; ic < 512; ic++) {
        const float* ip = in + (size_t)((b * 512 + ic)) * 4096;
        for (int i = t; i < 1296; i += 256) {
            int r = i / 36, c = i - r * 36;
            int gy = ty0 + r - 2, gx = tx0 + c - 2;
            tile[r][c] = (gy >= 0 && gy < 64 && gx >= 0 && gx < 64) ? ip[(gy << 6) + gx] : 0.f;
        }
        __syncthreads();
        const float* wp = w + ic * 25;
#pragma unroll
        for (int ky = 0; ky < 5; ky++) {
#pragma unroll
            for (int kx = 0; kx < 5; kx++) {
                float w0 = wp[(oc0 + 0) * 12800 + ky * 5 + kx];
                float w1v = wp[(oc0 + 1) * 12800 + ky * 5 + kx];
                float w2v = wp[(oc0 + 2) * 12800 + ky * 5 + kx];
                float w3v = wp[(oc0 + 3) * 12800 + ky * 5 + kx];
#pragma unroll
                for (int p = 0; p < 4; p++) {
                    float iv = tile[r0 + 8 * p + ky][px + kx];
                    acc[p][0] += iv * w0;
                    acc[p][1] += iv * w1v;
                    acc[p][2] += iv * w2v;
                    acc[p][3] += iv * w3v;
                }
            }
        }
        __syncthreads();
    }
#pragma unroll
    for (int p = 0; p < 4; p++) {
        int gy = ty0 + r0 + 8 * p, gx = tx0 + px;
#pragma unroll
        for (int j = 0; j < 4; j++)
            out[(size_t)((b * 512 + oc0 + j)) * 4096 + (gy << 6) + gx] = acc[p][j] + bias[oc0 + j];
    }
}

// ---------------- patchify (B,512,64,64) f32 -> (B,1024,2048) bf16 ----------------
__global__ void patchify_kernel(const float* __restrict__ hn, u16* __restrict__ pout) {
    int idx = blockIdx.x * 256 + threadIdx.x;
    int kf = idx & 2047;
    int tk = (idx >> 11) & 1023;
    int b = idx >> 21;
    int c = kf >> 2;
    int a = (kf >> 1) & 1;
    int b2 = kf & 1;
    int ph = tk >> 5, pw = tk & 31;
    pout[idx] = f2b(hn[(size_t)((b * 512 + c)) * 4096 + (((ph << 1) + a) << 6) + (pw << 1) + b2]);
}

// ---------------- layernorm + modulate (fp32 in, fp32 or bf16 out) ----------------
template <typename OT>
__global__ __launch_bounds__(256) void ln_mod_kernel(const float* __restrict__ in, OT* __restrict__ out,
                                                     const float* __restrict__ g, const float* __restrict__ bt,
                                                     const float* __restrict__ shiftb, const float* __restrict__ scaleb,
                                                     int modStride, float eps) {
    int row = blockIdx.x;
    int b = row >> 10;
    int t = threadIdx.x;
    const float* p = in + ((size_t)row << 10);
    float4 x = ((const float4*)p)[t];
    float s = x.x + x.y + x.z + x.w;
    float sq = x.x * x.x + x.y * x.y + x.z * x.z + x.w * x.w;
    __shared__ float2 red[256];
    red[t] = make_float2(s, sq);
    __syncthreads();
    for (int st = 128; st > 0; st >>= 1) {
        if (t < st) { red[t].x += red[t + st].x; red[t].y += red[t + st].y; }
        __syncthreads();
    }
    float mean = red[0].x * (1.f / 1024.f);
    float var = red[0].y * (1.f / 1024.f) - mean * mean;
    float rstd = rsqrtf(var + eps);
    const float* sh = shiftb + b * modStride;
    const float* sc = scaleb + b * modStride;
    int c = t << 2;
    float o0, o1, o2, o3;
    {
        float xn = (x.x - mean) * rstd; if (g) xn = xn * g[c + 0] + bt[c + 0];
        o0 = xn * (1.f + sc[c + 0]) + sh[c + 0];
    }
    {
        float xn = (x.y - mean) * rstd; if (g) xn = xn * g[c + 1] + bt[c + 1];
        o1 = xn * (1.f + sc[c + 1]) + sh[c + 1];
    }
    {
        float xn = (x.z - mean) * rstd; if (g) xn = xn * g[c + 2] + bt[c + 2];
        o2 = xn * (1.f + sc[c + 2]) + sh[c + 2];
    }
    {
        float xn = (x.w - mean) * rstd; if (g) xn = xn * g[c + 3] + bt[c + 3];
        o3 = xn * (1.f + sc[c + 3]) + sh[c + 3];
    }
    if constexpr (sizeof(OT) == 4) {
        float4 o = make_float4(o0, o1, o2, o3);
        ((float4*)(out + ((size_t)row << 10)))[t] = o;
    } else {
        ushort4 o;
        o.x = f2b(o0); o.y = f2b(o1); o.z = f2b(o2); o.w = f2b(o3);
        ((ushort4*)(out + ((size_t)row << 10)))[t] = o;
    }
}

// ---------------- rope (in-place, bf16 (B,T,H,D)) ----------------
__global__ void rope_kernel(u16* __restrict__ p) {
    int idx = blockIdx.x * 256 + threadIdx.x;  // 2097152
    int j = idx & 31;
    int tt = (idx >> 9) & 1023;
    float inv = powf(10000.f, -(float)j * (1.f / 32.f));
    float ang = (float)tt * inv;
    float cs = cosf(ang), sn = sinf(ang);
    int h = (idx >> 5) & 15;
    int b = idx >> 19;
    size_t base = (size_t)(((b << 10) + tt)) * 1024 + (h << 6) + (j << 1);
    ushort2 v = *(ushort2*)&p[base];
    float x = b2f(v.x), yv = b2f(v.y);
    ushort2 o;
    o.x = f2b(x * cs - yv * sn);
    o.y = f2b(x * sn + yv * cs);
    *(ushort2*)&p[base] = o;
}

// ---------------- K transpose bf16: (B,T,H,D) -> (B,H,D,T) ----------------
__global__ void ktrans_kernel(const u16* __restrict__ k, u16* __restrict__ kT) {
    int idx = blockIdx.x * 256 + threadIdx.x;  // 4194304
    int s = idx & 1023;
    int d = (idx >> 10) & 63;
    int h = (idx >> 16) & 15;
    int b = idx >> 20;
    kT[idx] = k[(size_t)(((b << 10) + s)) * 1024 + (h << 6) + d];
}

// ---------------- fused attention, bf16 I/O, fp32 math ----------------
__global__ __launch_bounds__(256) void attn_kernel(const u16* __restrict__ q, const u16* __restrict__ kT,
                                                   const u16* __restrict__ v, u16* __restrict__ o) {
    int b = blockIdx.z, h = blockIdx.y, tq0 = blockIdx.x << 3;
    int t = threadIdx.x;
    __shared__ float qv[8][64];
    __shared__ float sc[8][1024];
    __shared__ float po[4][8][64];
    __shared__ float red[256];
    __shared__ float rowsum[8];
    for (int i = t; i < 512; i += 256) {
        int r = i >> 6, d = i & 63;
        qv[r][d] = b2f(q[(size_t)(((b << 10) + tq0 + r)) * 1024 + (h << 6) + d]);
    }
    __syncthreads();
    float4 acc4[8];
#pragma unroll
    for (int r = 0; r < 8; r++) acc4[r] = make_float4(0.f, 0.f, 0.f, 0.f);
    const u16* kTp = kT + (size_t)(((b << 4) + h) << 6) * 1024;
    for (int d = 0; d < 64; d++) {
        ushort4 ku = *(const ushort4*)&kTp[(d << 10) + (t << 2)];
        float k0 = b2f(ku.x), k1 = b2f(ku.y), k2 = b2f(ku.z), k3 = b2f(ku.w);
#pragma unroll
        for (int r = 0; r < 8; r++) {
            float qd = qv[r][d];
            acc4[r].x += k0 * qd; acc4[r].y += k1 * qd;
            acc4[r].z += k2 * qd; acc4[r].w += k3 * qd;
        }
    }
#pragma unroll
    for (int r = 0; r < 8; r++) {
        sc[r][(t << 2) + 0] = acc4[r].x * 0.125f;
        sc[r][(t << 2) + 1] = acc4[r].y * 0.125f;
        sc[r][(t << 2) + 2] = acc4[r].z * 0.125f;
        sc[r][(t << 2) + 3] = acc4[r].w * 0.125f;
    }
    __syncthreads();
    for (int r = 0; r < 8; r++) {
        float m = fmaxf(fmaxf(sc[r][(t << 2)], sc[r][(t << 2) + 1]),
                        fmaxf(sc[r][(t << 2) + 2], sc[r][(t << 2) + 3]));
        red[t] = m;
        __syncthreads();
        for (int st = 128; st > 0; st >>= 1) {
            if (t < st) red[t] = fmaxf(red[t], red[t + st]);
            __syncthreads();
        }
        float rmax = red[0];
        __syncthreads();
        float ssum = 0.f;
#pragma unroll
        for (int u = 0; u < 4; u++) {
            float e = __expf(sc[r][(t << 2) + u] - rmax);
            sc[r][(t << 2) + u] = e;
            ssum += e;
        }
        red[t] = ssum;
        __syncthreads();
        for (int st = 128; st > 0; st >>= 1) {
            if (t < st) red[t] += red[t + st];
            __syncthreads();
        }
        if (t == 0) rowsum[r] = red[0];
        __syncthreads();
    }
    int d = t & 63, c = t >> 6;
    float pacc[8];
#pragma unroll
    for (int r = 0; r < 8; r++) pacc[r] = 0.f;
    for (int i = 0; i < 256; i++) {
        int s = (c << 8) + i;
        float vv = b2f(v[(size_t)(((b << 10) + s)) * 1024 + (h << 6) + d]);
#pragma unroll
        for (int r = 0; r < 8; r++) pacc[r] += sc[r][s] * vv;
    }
#pragma unroll
    for (int r = 0; r < 8; r++) po[c][r][d] = pacc[r];
    __syncthreads();
    for (int i = t; i < 512; i += 256) {
        int r = i >> 6, dd = i & 63;
        float oo = (po[0][r][dd] + po[1][r][dd] + po[2][r][dd] + po[3][r][dd]) / rowsum[r];
        o[(size_t)(((b << 10) + tq0 + r)) * 1024 + (h << 6) + dd] = f2b(oo);
    }
}

// ---------------- small row-vector GEMM (fp32) ----------------
__global__ __launch_bounds__(256) void rowvec_gemm_kernel(const float* __restrict__ A, const float* __restrict__ W,
                                                          const float* __restrict__ bias, float* __restrict__ out,
                                                          int N, int K) {
    int wid = blockIdx.x * 4 + (threadIdx.x >> 6);
    int lane = threadIdx.x & 63;
    int b = wid / N, n = wid - b * N;
    const float* a = A + (size_t)b * K;
    const float* w = W + (size_t)n * K;
    float s = 0.f;
    for (int k = lane << 2; k < K; k += 256) {
        float4 av = *(const float4*)&a[k];
        float4 wv = *(const float4*)&w[k];
        s += av.x * wv.x + av.y * wv.y + av.z * wv.z + av.w * wv.w;
    }
#pragma unroll
    for (int off = 32; off > 0; off >>= 1) s += __shfl_xor(s, off);
    if (lane == 0) out[wid] = s + (bias ? bias[n] : 0.f);
}

// ---------------- final projection: (4096x1024) @ (16x1024)^T + bias (fp32) ----------------
__global__ __launch_bounds__(256) void fin_gemm_kernel(const float* __restrict__ zf, const float* __restrict__ w,
                                                       const float* __restrict__ bias, float* __restrict__ out) {
    int idx = blockIdx.x * 256 + threadIdx.x;  // 65536
    int m = idx >> 4, n = idx & 15;
    const float* a = zf + ((size_t)m << 10);
    const float* wp = w + ((size_t)n << 10);
    float s = 0.f;
    for (int k = 0; k < 1024; k += 4) {
        float4 av = *(const float4*)&a[k];
        float4 wv = *(const float4*)&wp[k];
        s += av.x * wv.x + av.y * wv.y + av.z * wv.z + av.w * wv.w;
    }
    out[idx] = s + bias[n];
}

// ---------------- unpatchify -> (B,4,64,64) ----------------
__global__ void unpatch_kernel(const float* __restrict__ ot, float* __restrict__ out) {
    int idx = blockIdx.x * 256 + threadIdx.x;  // 65536
    int x = idx & 63;
    int yy = (idx >> 6) & 63;
    int ci = (idx >> 12) & 3;
    int b = idx >> 14;
    out[idx] = ot[(size_t)(((b << 10) + ((yy >> 1) << 5) + (x >> 1))) * 16 + (((yy & 1) << 1) + (x & 1)) * 4 + ci];
}

// ---------------- host orchestration ----------------
extern "C" void kernel_launch(void* const* d_in, const int* in_sizes, int n_in,
                              void* d_out, int out_size, void* d_ws, size_t ws_size,
                              hipStream_t stream) {
    const float* x       = (const float*)d_in[0];
    const float* tin     = (const float*)d_in[1];
    const int*   y       = (const int*)d_in[2];
    const float* conv1_w = (const float*)d_in[3];
    const float* conv1_b = (const float*)d_in[4];
    const float* gn1_g   = (const float*)d_in[5];
    const float* gn1_b   = (const float*)d_in[6];
    const float* conv2_w = (const float*)d_in[7];
    const float* conv2_b = (const float*)d_in[8];
    const float* gn2_g   = (const float*)d_in[9];
    const float* gn2_b   = (const float*)d_in[10];
    const float* xemb_w  = (const float*)d_in[11];
    const float* xemb_b  = (const float*)d_in[12];
    const float* t1_w    = (const float*)d_in[13];
    const float* t1_b    = (const float*)d_in[14];
    const float* t2_w    = (const float*)d_in[15];
    const float* t2_b    = (const float*)d_in[16];
    const float* y_emb   = (const float*)d_in[17];
    const float* wq      = (const float*)d_in[18];
    const float* wk      = (const float*)d_in[19];
    const float* wv      = (const float*)d_in[20];
    const float* wo      = (const float*)d_in[21];
    const float* w1      = (const float*)d_in[22];
    const float* w3      = (const float*)d_in[23];   // dict order: w1, w3, w2
    const float* w2      = (const float*)d_in[24];
    const float* ada_w   = (const float*)d_in[25];
    const float* ada_b   = (const float*)d_in[26];
    const float* an_g    = (const float*)d_in[27];
    const float* an_b    = (const float*)d_in[28];
    const float* fn_g    = (const float*)d_in[29];
    const float* fn_b    = (const float*)d_in[30];
    const float* fin_ada_w = (const float*)d_in[31];
    const float* fin_ada_b = (const float*)d_in[32];
    const float* fin_w   = (const float*)d_in[33];
    const float* fin_b   = (const float*)d_in[34];

    char* wsb = (char*)d_ws;
    // byte layout (total ~110.5 MB; ws_size proven >= 124 MB by round-1 usage)
    float* Z    = (float*)(wsb + 0);               // 16 MB residual stream (fp32)
    u16*  Wbf   = (u16*)(wsb + (16ull << 20));     // 18 MB per-layer bf16 weights
    u16*  HHb   = (u16*)(wsb + (34ull << 20));     // 8 MB ln/mod output bf16
    u16*  Qb    = (u16*)(wsb + (42ull << 20));     // 8 MB
    u16*  Kb    = (u16*)(wsb + (50ull << 20));     // 8 MB
    u16*  Vb    = (u16*)(wsb + (58ull << 20));     // 8 MB
    u16*  KTb   = (u16*)(wsb + (66ull << 20));     // 8 MB
    u16*  AOb   = (u16*)(wsb + (74ull << 20));     // 8 MB attn out bf16
    u16*  F1b   = (u16*)(wsb + (82ull << 20));     // 23.1 MB ff hidden bf16
    // stem-phase overlays (dead once the transformer starts)
    float* A0f  = (float*)(wsb + (42ull << 20));   // 33.6 MB
    float* A1f  = (float*)(wsb + (76ull << 20));   // 33.6 MB (ends ~109.6 MB)
    u16*  PATb  = (u16*)(wsb + (16ull << 20));     // 16.8 MB patches bf16
    u16*  XWb   = (u16*)(wsb + (34ull << 20));     // 4 MB xemb_w bf16
    float* ZF   = (float*)(wsb + (42ull << 20));   // final zf fp32 (over Qb/Kb)
    float* SM   = (float*)(wsb + (110ull << 20));  // small buffers
    float* TMB  = SM;            // 4096
    float* CSI  = TMB + 4096;    // 4096
    float* MODS = CSI + 4096;    // 24576
    float* FM   = MODS + 24576;  // 8192
    float* OT   = FM + 8192;     // 65536

    // conditioning
    temb1_kernel<<<16, 256, 0, stream>>>(tin, t1_w, t1_b, TMB);
    temb2_kernel<<<1024, 256, 0, stream>>>(TMB, t2_w, t2_b, y_emb, y, CSI);

    // conv stem (fp32)
    conv1_kernel<<<32768, 256, 0, stream>>>(x, conv1_w, conv1_b, A0f);
    silu_gn_kernel<<<128, 256, 0, stream>>>(A0f, A1f, gn1_g, gn1_b);
    conv2_kernel<<<dim3(4, 128, 4), 256, 0, stream>>>(A1f, conv2_w, conv2_b, A0f);
    silu_gn_kernel<<<128, 256, 0, stream>>>(A0f, A1f, gn2_g, gn2_b);
    patchify_kernel<<<32768, 256, 0, stream>>>(A1f, PATb);
    f2bN_kernel<<<2048, 256, 0, stream>>>(xemb_w, nullptr, nullptr, nullptr, XWb, 524288, 1);
    mfma_gemm_kernel<<<dim3(8, 32), 256, 0, stream>>>(PATb, XWb, 4096, 1024, 2048,
                                                      Z, nullptr, xemb_b, nullptr, nullptr, 0);

    for (int i = 0; i < NLAYERS; i++) {
        const float* wq_i = wq + (size_t)i * 1048576;
        const float* wk_i = wk + (size_t)i * 1048576;
        const float* wv_i = wv + (size_t)i * 1048576;
        const float* wo_i = wo + (size_t)i * 1048576;
        const float* w1_i = w1 + (size_t)i * 2883584;
        const float* w3_i = w3 + (size_t)i * 2883584;
        const float* w2_i = w2 + (size_t)i * 2883584;
        const float* ada_w_i = ada_w + (size_t)i * 6291456;
        const float* ada_b_i = ada_b + (size_t)i * 6144;

        // bf16 weights for attn part: [wq|wk|wv|wo]
        f2bN_kernel<<<4096, 256, 0, stream>>>(wq_i, wk_i, wv_i, wo_i, Wbf, 262144, 4);
        // adaLN mods (fp32)
        rowvec_gemm_kernel<<<6144, 256, 0, stream>>>(CSI, ada_w_i, ada_b_i, MODS, 6144, 1024);
        // attn branch
        ln_mod_kernel<u16><<<4096, 256, 0, stream>>>(Z, HHb, an_g + i * 1024, an_b + i * 1024,
                                                     MODS + 0, MODS + 1024, 6144, 1e-5f);
        mfma_gemm_kernel<<<dim3(8, 32), 256, 0, stream>>>(HHb, Wbf + 0ull, 4096, 1024, 1024,
                                                          nullptr, Qb, nullptr, nullptr, nullptr, 0);
        mfma_gemm_kernel<<<dim3(8, 32), 256, 0, stream>>>(HHb, Wbf + 1048576ull, 4096, 1024, 1024,
                                                          nullptr, Kb, nullptr, nullptr, nullptr, 0);
        mfma_gemm_kernel<<<dim3(8, 32), 256, 0, stream>>>(HHb, Wbf + 2097152ull, 4096, 1024, 1024,
                                                          nullptr, Vb, nullptr, nullptr, nullptr, 0);
        rope_kernel<<<8192, 256, 0, stream>>>(Qb);
        rope_kernel<<<8192, 256, 0, stream>>>(Kb);
        ktrans_kernel<<<16384, 256, 0, stream>>>(Kb, KTb);
        attn_kernel<<<dim3(128, 16, 4), 256, 0, stream>>>(Qb, KTb, Vb, AOb);
        mfma_gemm_kernel<<<dim3(8, 32), 256, 0, stream>>>(AOb, Wbf + 3145728ull, 4096, 1024, 1024,
                                                          nullptr, nullptr, nullptr, Z, MODS + 2048, 6144);
        // ff branch
        ln_mod_kernel<u16><<<4096, 256, 0, stream>>>(Z, HHb, fn_g + i * 1024, fn_b + i * 1024,
                                                     MODS + 3072, MODS + 4096, 6144, 1e-5f);
        f2bN_kernel<<<8448, 256, 0, stream>>>(w1_i, w3_i, w2_i, nullptr, Wbf, 720896, 3);
        mfma_gemm_swiglu_kernel<<<dim3(22, 32), 256, 0, stream>>>(HHb, Wbf, Wbf + 2883584ull,
                                                                  4096, 2816, 1024, F1b);
        mfma_gemm_kernel<<<dim3(8, 32), 256, 0, stream>>>(F1b, Wbf + 5767168ull, 4096, 1024, 2816,
                                                          nullptr, nullptr, nullptr, Z, MODS + 5120, 6144);
    }

    // final head
    rowvec_gemm_kernel<<<2048, 256, 0, stream>>>(CSI, fin_ada_w, fin_ada_b, FM, 2048, 1024);
    ln_mod_kernel<float><<<4096, 256, 0, stream>>>(Z, ZF, nullptr, nullptr, FM + 0, FM + 1024, 2048, 1e-6f);
    fin_gemm_kernel<<<256, 256, 0, stream>>>(ZF, fin_w, fin_b, OT);
    unpatch_kernel<<<256, 256, 0, stream>>>(OT, (float*)d_out);
}